// Round 11
// baseline (274.432 us; speedup 1.0000x reference)
//
#include <hip/hip_runtime.h>
#include <hip/hip_bf16.h>

#define T_DIM 2048
#define S_DIM 2048
#define B_DIM 2
#define E_DIM 1024
#define H_DIM 16
#define D_DIM 64
// softmax scale 0.125 and the 1/ln2 of exp are folded into qb at prep time:
// qb = bf16((q+qpos) * 0.125*log2(e)); then P = exp2(qb.k) exactly (no shift:
// shift cancels in P/l and e*lin; |z|<~43 so exp2(z), l stay in fp32 range).
#define EXP2S 0.18033688f
#define EXP2(x) __builtin_amdgcn_exp2f(x)

typedef unsigned short u16;
typedef unsigned int u32;
typedef float v4f __attribute__((ext_vector_type(4)));
typedef short v8s __attribute__((ext_vector_type(8)));
typedef short v4s __attribute__((ext_vector_type(4)));

__device__ __forceinline__ u16 f2bf(float f) {   // RNE
    union { float f; u32 u; } x; x.f = f;
    return (u16)((x.u + 0x7fffu + ((x.u >> 16) & 1u)) >> 16);
}
__device__ __forceinline__ u32 pkrn(float lo, float hi) {  // packed bf16 pair
    union { __hip_bfloat162 h; u32 u; } c;
    c.h = __float22bfloat162_rn(make_float2(lo, hi));
    return c.u;
}
__device__ __forceinline__ v4f mfma16(v8s a, v8s b, v4f c) {
    return __builtin_amdgcn_mfma_f32_16x16x32_bf16(a, b, c, 0, 0, 0);
}
__device__ __forceinline__ v4f mfma16x16(v4s a, v4s b, v4f c) {
    return __builtin_amdgcn_mfma_f32_16x16x16bf16_1k(a, b, c, 0, 0, 0);
}
__device__ __forceinline__ v8s ld8(const u16* p) {
    return *reinterpret_cast<const v8s*>(p);
}

// ---------------------------------------------------------------------------
// K0: fused prep. Blocks [0,16384): qb = bf16((q+qpos)*EXP2S), ks = bf16(k+kpos),
// Wb = bf16(W). Blocks [16384,17408): vt transpose (independent work).
// ---------------------------------------------------------------------------
__global__ __launch_bounds__(256) void prep_all(
    const float* __restrict__ q, const float* __restrict__ qp,
    const float* __restrict__ k, const float* __restrict__ kp,
    const float* __restrict__ W, const float* __restrict__ V,
    u16* __restrict__ qb, u16* __restrict__ ks, u16* __restrict__ Wb,
    u16* __restrict__ vt) {
    __shared__ float tile[64 * 65];
    int bx = blockIdx.x;
    int tid = threadIdx.x;
    if (bx < 16384) {
        int o = bx * 256 + tid;                          // (b,h,t,d)
        int d = o & 63, t = (o >> 6) & 2047, h = (o >> 17) & 15, b = o >> 21;
        int src = ((t * B_DIM + b) << 10) + (h << 6) + d; // (t,b,e)
        qb[o] = f2bf((q[src] + qp[src]) * EXP2S);
        ks[o] = f2bf(k[src] + kp[src]);
        if (o < E_DIM * E_DIM) Wb[o] = f2bf(W[o]);       // fused prep_w
        return;
    }
    // --- vt branch: vt[b][h][d][s] = bf16(V[s][b][h*64+d]) ---
    int vb = bx - 16384;                 // (bh, s-tile): 32 bh * 32 stiles
    int bh = vb >> 5;
    int s0 = (vb & 31) * 64;
    int b = bh >> 4, h = bh & 15;
    int quarter = tid >> 6, c = tid & 63;
    int boff = b * E_DIM + h * 64;
#pragma unroll
    for (int p = 0; p < 16; ++p) {
        int r = quarter * 16 + p;
        tile[r * 65 + c] = V[(size_t)(s0 + r) * (B_DIM * E_DIM) + boff + c];
    }
    __syncthreads();
#pragma unroll
    for (int p = 0; p < 16; ++p) {
        int d = quarter * 16 + p;
        vt[(size_t)bh * (D_DIM * S_DIM) + (size_t)d * S_DIM + s0 + c] = f2bf(tile[c * 65 + d]);
    }
}

// ---------------------------------------------------------------------------
// K1: attention output + row sums. grid (bh, t-tile128) = 512 blocks, 256 thr.
// Swapped QK^T -> P in registers (16x16x16 A-frag layout); PV reg-direct.
// VALU diet: no fma before exp (scale folded into qb), hardware cvt_pk pack.
// K/V s-tile 64 in LDS, double-buffered via register relay. (no setprio:
// R10 A/B showed +3.5us regression on this barrier-synced structure)
// ---------------------------------------------------------------------------
#define PITCH 72   // 64 elems + 8 pad (144 B rows)
__global__ __launch_bounds__(256) void attn_pv(
    const u16* __restrict__ qb, const u16* __restrict__ ks, const u16* __restrict__ vt,
    float* __restrict__ lin, u16* __restrict__ Xb) {
    __shared__ u16 Kl[2][64 * PITCH];   // 18 KB
    __shared__ u16 Vl[2][64 * PITCH];   // 18 KB

    int bx = blockIdx.x;
    int bh = bx >> 4;
    int b = bh >> 4, h = bh & 15;
    int tid = threadIdx.x;
    int w = tid >> 6;
    int tbase = (bx & 15) * 128 + w * 32;
    int lane = tid & 63;
    int m = lane & 15, g = lane >> 4;

    // staging: thread -> (row 0..63, 16-elem quarter)
    int srow = tid >> 2;
    int sqtr = (tid & 3) * 16;

    uint4 kr0, kr1, vr0, vr1;
    auto load_stage = [&](int s0) {
        const uint4* kp = reinterpret_cast<const uint4*>(
            ks + ((size_t)bh * S_DIM + s0 + srow) * 64 + sqtr);
        kr0 = kp[0]; kr1 = kp[1];
        const uint4* vp = reinterpret_cast<const uint4*>(
            vt + (size_t)bh * (D_DIM * S_DIM) + (size_t)srow * S_DIM + s0 + sqtr);
        vr0 = vp[0]; vr1 = vp[1];
    };
    auto write_stage = [&](int buf) {
        uint4* kd = reinterpret_cast<uint4*>(&Kl[buf][srow * PITCH + sqtr]);
        kd[0] = kr0; kd[1] = kr1;
        uint4* vd = reinterpret_cast<uint4*>(&Vl[buf][srow * PITCH + sqtr]);
        vd[0] = vr0; vd[1] = vr1;
    };

    // Q-frags (B-operand of swapped QK): 2 groups of 16 t-rows
    const u16* qrow = qb + ((size_t)bh * T_DIM + tbase + m) * 64 + g * 8;
    v8s aq[2][2];
    aq[0][0] = ld8(qrow);        aq[0][1] = ld8(qrow + 32);
    aq[1][0] = ld8(qrow + 1024); aq[1][1] = ld8(qrow + 1024 + 32);

    v4f O[2][4];
    float lacc[2] = {0.f, 0.f};
#pragma unroll
    for (int tr = 0; tr < 2; ++tr)
#pragma unroll
        for (int dd = 0; dd < 4; ++dd) O[tr][dd] = (v4f){0.f, 0.f, 0.f, 0.f};

    load_stage(0);
    write_stage(0);
    load_stage(64);
    __syncthreads();

    for (int it = 0; it < 32; ++it) {
        int buf = it & 1;
        const u16* Kb = Kl[buf];
        const u16* Vb = Vl[buf];
#pragma unroll
        for (int ss = 0; ss < 4; ++ss) {
            v8s kf0 = ld8(&Kb[(ss * 16 + m) * PITCH + g * 8]);
            v8s kf1 = ld8(&Kb[(ss * 16 + m) * PITCH + 32 + g * 8]);
            v4s pa0, pa1;
            {   // tr = 0: z rows = s (16ss+4g+r), cols = t (tbase+m)
                v4f z = {0.f, 0.f, 0.f, 0.f};
                z = mfma16(kf0, aq[0][0], z);
                z = mfma16(kf1, aq[0][1], z);
                float e0 = EXP2(z[0]);
                float e1 = EXP2(z[1]);
                float e2 = EXP2(z[2]);
                float e3 = EXP2(z[3]);
                lacc[0] += (e0 + e1) + (e2 + e3);
                union { u32 u[2]; v4s s; } pk_;
                pk_.u[0] = pkrn(e0, e1);
                pk_.u[1] = pkrn(e2, e3);
                pa0 = pk_.s;
            }
            {   // tr = 1
                v4f z = {0.f, 0.f, 0.f, 0.f};
                z = mfma16(kf0, aq[1][0], z);
                z = mfma16(kf1, aq[1][1], z);
                float e0 = EXP2(z[0]);
                float e1 = EXP2(z[1]);
                float e2 = EXP2(z[2]);
                float e3 = EXP2(z[3]);
                lacc[1] += (e0 + e1) + (e2 + e3);
                union { u32 u[2]; v4s s; } pk_;
                pk_.u[0] = pkrn(e0, e1);
                pk_.u[1] = pkrn(e2, e3);
                pa1 = pk_.s;
            }
            // PV for this ss-block: B-frag = V[s=16ss+4g+j][d=dd*16+m] (8B read)
#pragma unroll
            for (int dd = 0; dd < 4; ++dd) {
                v4s bv = *reinterpret_cast<const v4s*>(
                    &Vb[(dd * 16 + m) * PITCH + ss * 16 + g * 4]);
                O[0][dd] = mfma16x16(pa0, bv, O[0][dd]);
                O[1][dd] = mfma16x16(pa1, bv, O[1][dd]);
            }
        }
        // ---- relay: stage next tile, prefetch tile after ----
        if (it + 1 < 32) {
            write_stage(buf ^ 1);
            if (it + 2 < 32) load_stage((it + 2) * 64);
        }
        __syncthreads();
    }

    // l lives per-lane at t = tbase + tr*16 + m; reduce over g (lane bits 4-5)
#pragma unroll
    for (int tr = 0; tr < 2; ++tr) {
        lacc[tr] += __shfl_xor(lacc[tr], 16);
        lacc[tr] += __shfl_xor(lacc[tr], 32);
        float linv = 1.0f / lacc[tr];
        if (lane < 16) lin[(size_t)bh * T_DIM + tbase + tr * 16 + m] = linv;
#pragma unroll
        for (int r = 0; r < 4; ++r) {
            float lr = __shfl(linv, g * 4 + r);   // l for t-row g*4+r
            int t = tbase + tr * 16 + g * 4 + r;
#pragma unroll
            for (int dd = 0; dd < 4; ++dd)
                Xb[((size_t)t * B_DIM + b) * E_DIM + h * 64 + dd * 16 + m] =
                    f2bf(O[tr][dd][r] * lr);
        }
    }
}

// ---------------------------------------------------------------------------
// K2: fused attn_avg + linear (independent consumers of attn_pv's outputs;
// merged to cut a launch gap and co-schedule VALU-heavy avg with
// MFMA/LDS-heavy linear). One 30 KB shared buffer aliased per branch
// (union not sum -> avg keeps >=4 blocks/CU).
// Blocks [0,1024): attn_avg -> out1 (B,T,S).
// Blocks [1024,1536): linear: out0 = Xb @ Wb^T + bias + query. Tile 64x128,
// BK=32 (32 k-iters), LDS Al 2x5KB + Wl 2x10KB = 30 KB.
// ---------------------------------------------------------------------------
#define PITCHL 40   // 32 elems + 8 pad (linear BK=32 rows)
__global__ __launch_bounds__(256, 4) void avg_linear(
    const u16* __restrict__ qb, const u16* __restrict__ ks,
    const float* __restrict__ lin, float* __restrict__ out1,
    const u16* __restrict__ Xb, const u16* __restrict__ Wb,
    const float* __restrict__ bias, const float* __restrict__ query,
    float* __restrict__ out0) {
    __shared__ __align__(16) char smem[30720];
    int bx = blockIdx.x;
    int tid = threadIdx.x;
    int w = tid >> 6;
    int lane = tid & 63, m = lane & 15, g = lane >> 4;

    if (bx < 1024) {
        // ================= attn_avg branch =================
        u16* Kl0 = reinterpret_cast<u16*>(smem);            // [2][64*PITCH]
        int b = bx >> 9;
        int tt = (bx >> 5) & 15;
        int st = bx & 31;
        int tbase = tt * 128 + w * 32;
        int sbase = st * 64;

        int srow = tid >> 2;
        int sqtr = (tid & 3) * 16;

        uint4 kr0, kr1;
        auto load_stage = [&](int h) {
            const uint4* kp = reinterpret_cast<const uint4*>(
                ks + ((size_t)(b * 16 + h) * S_DIM + sbase + srow) * 64 + sqtr);
            kr0 = kp[0]; kr1 = kp[1];
        };
        auto write_stage = [&](int buf) {
            uint4* kd = reinterpret_cast<uint4*>(&Kl0[buf * (64 * PITCH) + srow * PITCH + sqtr]);
            kd[0] = kr0; kd[1] = kr1;
        };

        v8s aqc00, aqc01, aqc10, aqc11, aqn00, aqn01, aqn10, aqn11;
        float livc[2][4], livn[2][4];
        auto load_q = [&](int h, v8s& a00, v8s& a01, v8s& a10, v8s& a11, float (&liv)[2][4]) {
            int bh = b * 16 + h;
            const u16* qrow = qb + ((size_t)bh * T_DIM + tbase + m) * 64 + g * 8;
            a00 = ld8(qrow);        a01 = ld8(qrow + 32);
            a10 = ld8(qrow + 1024); a11 = ld8(qrow + 1024 + 32);
#pragma unroll
            for (int tr = 0; tr < 2; ++tr)
#pragma unroll
                for (int r = 0; r < 4; ++r)
                    liv[tr][r] = lin[(size_t)bh * T_DIM + tbase + tr * 16 + g * 4 + r] * (1.0f / 16.0f);
        };

        v4f AVG[2][4];
#pragma unroll
        for (int tr = 0; tr < 2; ++tr)
#pragma unroll
            for (int ss = 0; ss < 4; ++ss) AVG[tr][ss] = (v4f){0.f, 0.f, 0.f, 0.f};

        load_stage(0);
        write_stage(0);
        load_stage(1);
        load_q(0, aqc00, aqc01, aqc10, aqc11, livc);
        __syncthreads();

        for (int h = 0; h < H_DIM; ++h) {
            int buf = h & 1;
            if (h + 1 < H_DIM) load_q(h + 1, aqn00, aqn01, aqn10, aqn11, livn);

            const u16* Kb = &Kl0[buf * (64 * PITCH)];
#pragma unroll
            for (int ss = 0; ss < 4; ++ss) {
                v8s kf0 = ld8(&Kb[(ss * 16 + m) * PITCH + g * 8]);
                v8s kf1 = ld8(&Kb[(ss * 16 + m) * PITCH + 32 + g * 8]);
                {
                    v4f z = {0.f, 0.f, 0.f, 0.f};
                    z = mfma16(aqc00, kf0, z);
                    z = mfma16(aqc01, kf1, z);
#pragma unroll
                    for (int r = 0; r < 4; ++r)
                        AVG[0][ss][r] += EXP2(z[r]) * livc[0][r];
                }
                {
                    v4f z = {0.f, 0.f, 0.f, 0.f};
                    z = mfma16(aqc10, kf0, z);
                    z = mfma16(aqc11, kf1, z);
#pragma unroll
                    for (int r = 0; r < 4; ++r)
                        AVG[1][ss][r] += EXP2(z[r]) * livc[1][r];
                }
            }
            if (h + 1 < H_DIM) {
                write_stage(buf ^ 1);
                if (h + 2 < H_DIM) load_stage(h + 2);
            }
            __syncthreads();
            aqc00 = aqn00; aqc01 = aqn01; aqc10 = aqn10; aqc11 = aqn11;
#pragma unroll
            for (int tr = 0; tr < 2; ++tr)
#pragma unroll
                for (int r = 0; r < 4; ++r) livc[tr][r] = livn[tr][r];
        }
#pragma unroll
        for (int tr = 0; tr < 2; ++tr)
#pragma unroll
            for (int ss = 0; ss < 4; ++ss)
#pragma unroll
                for (int r = 0; r < 4; ++r) {
                    int t = tbase + tr * 16 + g * 4 + r;
                    out1[((size_t)b * T_DIM + t) * S_DIM + sbase + ss * 16 + m] = AVG[tr][ss][r];
                }
        return;
    }

    // ================= linear branch (BK=32) =================
    u16* Al = reinterpret_cast<u16*>(smem);                     // [2][64*PITCHL]  10 KB
    u16* Wl = reinterpret_cast<u16*>(smem) + 2 * 64 * PITCHL;   // [2][128*PITCHL] 20 KB
    int lb = bx - 1024;
    int it = lb >> 3, jt = lb & 7;

    // staging maps
    int arow = tid >> 2, ac = (tid & 3) * 8;     // A: 64 rows x 16 B per thread
    int wrow = tid >> 1, wc = (tid & 1) * 16;    // W: 128 rows x 32 B per thread

    uint4 ar0, wr0, wr1;
    auto load_stage = [&](int k0) {
        ar0 = *reinterpret_cast<const uint4*>(
            Xb + (size_t)(it * 64 + arow) * E_DIM + k0 + ac);
        const uint4* wp = reinterpret_cast<const uint4*>(
            Wb + (size_t)(jt * 128 + wrow) * E_DIM + k0 + wc);
        wr0 = wp[0]; wr1 = wp[1];
    };
    auto write_stage = [&](int buf) {
        *reinterpret_cast<uint4*>(&Al[buf * (64 * PITCHL) + arow * PITCHL + ac]) = ar0;
        uint4* wd = reinterpret_cast<uint4*>(&Wl[buf * (128 * PITCHL) + wrow * PITCHL + wc]);
        wd[0] = wr0; wd[1] = wr1;
    };

    v4f acc[4][2];
#pragma unroll
    for (int tr = 0; tr < 4; ++tr)
#pragma unroll
        for (int nn = 0; nn < 2; ++nn) acc[tr][nn] = (v4f){0.f, 0.f, 0.f, 0.f};

    load_stage(0);
    write_stage(0);
    load_stage(32);
    __syncthreads();

    for (int itk = 0; itk < 32; ++itk) {
        int buf = itk & 1;
        const u16* Ab = &Al[buf * (64 * PITCHL)];
        const u16* Ws = &Wl[buf * (128 * PITCHL)];
        v8s af[4], wf[2];
#pragma unroll
        for (int tr = 0; tr < 4; ++tr)
            af[tr] = ld8(&Ab[(tr * 16 + m) * PITCHL + g * 8]);
#pragma unroll
        for (int nn = 0; nn < 2; ++nn)
            wf[nn] = ld8(&Ws[((w * 2 + nn) * 16 + m) * PITCHL + g * 8]);
#pragma unroll
        for (int tr = 0; tr < 4; ++tr)
#pragma unroll
            for (int nn = 0; nn < 2; ++nn)
                acc[tr][nn] = mfma16(af[tr], wf[nn], acc[tr][nn]);
        if (itk + 1 < 32) {
            write_stage(buf ^ 1);
            if (itk + 2 < 32) load_stage((itk + 2) * 32);
        }
        __syncthreads();
    }

    // epilogue: bias + residual(query) + fp32 store
#pragma unroll
    for (int tr = 0; tr < 4; ++tr)
#pragma unroll
        for (int nn = 0; nn < 2; ++nn) {
            int col = jt * 128 + (w * 2 + nn) * 16 + m;
            float bv = bias[col];
#pragma unroll
            for (int r = 0; r < 4; ++r) {
                int row = it * 64 + tr * 16 + g * 4 + r;
                out0[(size_t)row * E_DIM + col] =
                    acc[tr][nn][r] + bv + query[(size_t)row * E_DIM + col];
            }
        }
}

// ---------------------------------------------------------------------------
extern "C" void kernel_launch(void* const* d_in, const int* in_sizes, int n_in,
                              void* d_out, int out_size, void* d_ws, size_t ws_size,
                              hipStream_t stream) {
    const float* query = (const float*)d_in[0];
    const float* key   = (const float*)d_in[1];
    const float* value = (const float*)d_in[2];
    const float* qpos  = (const float*)d_in[3];
    const float* kpos  = (const float*)d_in[4];
    const float* W     = (const float*)d_in[5];
    const float* bias  = (const float*)d_in[6];

    char* ws = (char*)d_ws;
    u16*   qb  = (u16*)(ws);                              //  8 MB
    u16*   ks  = (u16*)(ws + (size_t)( 8u << 20));        //  8 MB
    u16*   vt  = (u16*)(ws + (size_t)(16u << 20));        //  8 MB
    u16*   Wb  = (u16*)(ws + (size_t)(24u << 20));        //  2 MB
    float* lin = (float*)(ws + (size_t)(26u << 20));      // 256 KB
    u16*   Xb  = (u16*)(ws + (size_t)(27u << 20));        //  8 MB (35 MB total)

    float* out0 = (float*)d_out;
    float* out1 = out0 + (size_t)T_DIM * B_DIM * E_DIM;

    prep_all<<<16384 + B_DIM * H_DIM * (S_DIM / 64), 256, 0, stream>>>(
        query, qpos, key, kpos, W, value, qb, ks, Wb, vt);
    attn_pv<<<B_DIM * H_DIM * (T_DIM / 128), 256, 0, stream>>>(qb, ks, vt, lin, Xb);
    avg_linear<<<B_DIM * (T_DIM / 128) * (S_DIM / 64) + (T_DIM * B_DIM / 64) * (E_DIM / 128),
                 256, 0, stream>>>(qb, ks, lin, out1, Xb, Wb, bias, query, out0);
}

// Round 12
// 257.316 us; speedup vs baseline: 1.0665x; 1.0665x over previous
//
#include <hip/hip_runtime.h>
#include <hip/hip_bf16.h>

#define T_DIM 2048
#define S_DIM 2048
#define B_DIM 2
#define E_DIM 1024
#define H_DIM 16
#define D_DIM 64
// softmax scale 0.125 and the 1/ln2 of exp are folded into qb at prep time:
// qb = bf16((q+qpos) * 0.125*log2(e)); then P = exp2(qb.k) exactly (no shift:
// shift cancels in P/l and e*lin; |z|<~43 so exp2(z), l stay in fp32 range).
#define EXP2S 0.18033688f
#define EXP2(x) __builtin_amdgcn_exp2f(x)

typedef unsigned short u16;
typedef unsigned int u32;
typedef float v4f __attribute__((ext_vector_type(4)));
typedef short v8s __attribute__((ext_vector_type(8)));
typedef short v4s __attribute__((ext_vector_type(4)));

__device__ __forceinline__ u16 f2bf(float f) {   // RNE
    union { float f; u32 u; } x; x.f = f;
    return (u16)((x.u + 0x7fffu + ((x.u >> 16) & 1u)) >> 16);
}
__device__ __forceinline__ u32 pkrn(float lo, float hi) {  // packed bf16 pair
    union { __hip_bfloat162 h; u32 u; } c;
    c.h = __float22bfloat162_rn(make_float2(lo, hi));
    return c.u;
}
__device__ __forceinline__ v4f mfma16(v8s a, v8s b, v4f c) {
    return __builtin_amdgcn_mfma_f32_16x16x32_bf16(a, b, c, 0, 0, 0);
}
__device__ __forceinline__ v4f mfma16x16(v4s a, v4s b, v4f c) {
    return __builtin_amdgcn_mfma_f32_16x16x16bf16_1k(a, b, c, 0, 0, 0);
}
__device__ __forceinline__ v8s ld8(const u16* p) {
    return *reinterpret_cast<const v8s*>(p);
}

// ---------------------------------------------------------------------------
// K0a: qb = bf16((q+qpos)*EXP2S); ks = bf16(k+kpos); Wb = bf16(W) (fused).
// ---------------------------------------------------------------------------
__global__ __launch_bounds__(256) void prep_qk(
    const float* __restrict__ q, const float* __restrict__ qp,
    const float* __restrict__ k, const float* __restrict__ kp,
    const float* __restrict__ W,
    u16* __restrict__ qb, u16* __restrict__ ks, u16* __restrict__ Wb) {
    int o = blockIdx.x * 256 + threadIdx.x;          // (b,h,t,d)
    int d = o & 63, t = (o >> 6) & 2047, h = (o >> 17) & 15, b = o >> 21;
    int src = ((t * B_DIM + b) << 10) + (h << 6) + d; // (t,b,e)
    qb[o] = f2bf((q[src] + qp[src]) * EXP2S);
    ks[o] = f2bf(k[src] + kp[src]);
    if (o < E_DIM * E_DIM) Wb[o] = f2bf(W[o]);       // fused prep_w
}

// K0c: vt[b][h][d][s] = bf16(V[s][b][h*64+d])  — tiled transpose
__global__ __launch_bounds__(256) void prep_vt(const float* __restrict__ V, u16* __restrict__ vt) {
    __shared__ float tile[64 * 65];
    int bx = blockIdx.x;                 // (bh, s-tile): 32 bh * 32 stiles
    int bh = bx >> 5;
    int s0 = (bx & 31) * 64;
    int b = bh >> 4, h = bh & 15;
    int tid = threadIdx.x;
    int quarter = tid >> 6, c = tid & 63;
    int boff = b * E_DIM + h * 64;
#pragma unroll
    for (int p = 0; p < 16; ++p) {
        int r = quarter * 16 + p;
        tile[r * 65 + c] = V[(size_t)(s0 + r) * (B_DIM * E_DIM) + boff + c];
    }
    __syncthreads();
#pragma unroll
    for (int p = 0; p < 16; ++p) {
        int d = quarter * 16 + p;
        vt[(size_t)bh * (D_DIM * S_DIM) + (size_t)d * S_DIM + s0 + c] = f2bf(tile[c * 65 + d]);
    }
}

// ---------------------------------------------------------------------------
// K1: attention output + row sums. grid (bh, t-tile128) = 512 blocks, 256 thr.
// Swapped QK^T -> P in registers (16x16x16 A-frag layout); PV reg-direct.
// VALU diet: no fma before exp (scale folded into qb), hardware cvt_pk pack.
// K/V s-tile 64 in LDS, double-buffered via register relay.
// No setprio (R10 A/B: +3.5us regression on this barrier-synced structure).
// ---------------------------------------------------------------------------
#define PITCH 72   // 64 elems + 8 pad (144 B rows)
__global__ __launch_bounds__(256) void attn_pv(
    const u16* __restrict__ qb, const u16* __restrict__ ks, const u16* __restrict__ vt,
    float* __restrict__ lin, u16* __restrict__ Xb) {
    __shared__ u16 Kl[2][64 * PITCH];   // 18 KB
    __shared__ u16 Vl[2][64 * PITCH];   // 18 KB

    int bx = blockIdx.x;
    int bh = bx >> 4;
    int b = bh >> 4, h = bh & 15;
    int tid = threadIdx.x;
    int w = tid >> 6;
    int tbase = (bx & 15) * 128 + w * 32;
    int lane = tid & 63;
    int m = lane & 15, g = lane >> 4;

    // staging: thread -> (row 0..63, 16-elem quarter)
    int srow = tid >> 2;
    int sqtr = (tid & 3) * 16;

    uint4 kr0, kr1, vr0, vr1;
    auto load_stage = [&](int s0) {
        const uint4* kp = reinterpret_cast<const uint4*>(
            ks + ((size_t)bh * S_DIM + s0 + srow) * 64 + sqtr);
        kr0 = kp[0]; kr1 = kp[1];
        const uint4* vp = reinterpret_cast<const uint4*>(
            vt + (size_t)bh * (D_DIM * S_DIM) + (size_t)srow * S_DIM + s0 + sqtr);
        vr0 = vp[0]; vr1 = vp[1];
    };
    auto write_stage = [&](int buf) {
        uint4* kd = reinterpret_cast<uint4*>(&Kl[buf][srow * PITCH + sqtr]);
        kd[0] = kr0; kd[1] = kr1;
        uint4* vd = reinterpret_cast<uint4*>(&Vl[buf][srow * PITCH + sqtr]);
        vd[0] = vr0; vd[1] = vr1;
    };

    // Q-frags (B-operand of swapped QK): 2 groups of 16 t-rows
    const u16* qrow = qb + ((size_t)bh * T_DIM + tbase + m) * 64 + g * 8;
    v8s aq[2][2];
    aq[0][0] = ld8(qrow);        aq[0][1] = ld8(qrow + 32);
    aq[1][0] = ld8(qrow + 1024); aq[1][1] = ld8(qrow + 1024 + 32);

    v4f O[2][4];
    float lacc[2] = {0.f, 0.f};
#pragma unroll
    for (int tr = 0; tr < 2; ++tr)
#pragma unroll
        for (int dd = 0; dd < 4; ++dd) O[tr][dd] = (v4f){0.f, 0.f, 0.f, 0.f};

    load_stage(0);
    write_stage(0);
    load_stage(64);
    __syncthreads();

    for (int it = 0; it < 32; ++it) {
        int buf = it & 1;
        const u16* Kb = Kl[buf];
        const u16* Vb = Vl[buf];
#pragma unroll
        for (int ss = 0; ss < 4; ++ss) {
            v8s kf0 = ld8(&Kb[(ss * 16 + m) * PITCH + g * 8]);
            v8s kf1 = ld8(&Kb[(ss * 16 + m) * PITCH + 32 + g * 8]);
            v4s pa0, pa1;
            {   // tr = 0: z rows = s (16ss+4g+r), cols = t (tbase+m)
                v4f z = {0.f, 0.f, 0.f, 0.f};
                z = mfma16(kf0, aq[0][0], z);
                z = mfma16(kf1, aq[0][1], z);
                float e0 = EXP2(z[0]);
                float e1 = EXP2(z[1]);
                float e2 = EXP2(z[2]);
                float e3 = EXP2(z[3]);
                lacc[0] += (e0 + e1) + (e2 + e3);
                union { u32 u[2]; v4s s; } pk_;
                pk_.u[0] = pkrn(e0, e1);
                pk_.u[1] = pkrn(e2, e3);
                pa0 = pk_.s;
            }
            {   // tr = 1
                v4f z = {0.f, 0.f, 0.f, 0.f};
                z = mfma16(kf0, aq[1][0], z);
                z = mfma16(kf1, aq[1][1], z);
                float e0 = EXP2(z[0]);
                float e1 = EXP2(z[1]);
                float e2 = EXP2(z[2]);
                float e3 = EXP2(z[3]);
                lacc[1] += (e0 + e1) + (e2 + e3);
                union { u32 u[2]; v4s s; } pk_;
                pk_.u[0] = pkrn(e0, e1);
                pk_.u[1] = pkrn(e2, e3);
                pa1 = pk_.s;
            }
            // PV for this ss-block: B-frag = V[s=16ss+4g+j][d=dd*16+m] (8B read)
#pragma unroll
            for (int dd = 0; dd < 4; ++dd) {
                v4s bv = *reinterpret_cast<const v4s*>(
                    &Vb[(dd * 16 + m) * PITCH + ss * 16 + g * 4]);
                O[0][dd] = mfma16x16(pa0, bv, O[0][dd]);
                O[1][dd] = mfma16x16(pa1, bv, O[1][dd]);
            }
        }
        // ---- relay: stage next tile, prefetch tile after ----
        if (it + 1 < 32) {
            write_stage(buf ^ 1);
            if (it + 2 < 32) load_stage((it + 2) * 64);
        }
        __syncthreads();
    }

    // l lives per-lane at t = tbase + tr*16 + m; reduce over g (lane bits 4-5)
#pragma unroll
    for (int tr = 0; tr < 2; ++tr) {
        lacc[tr] += __shfl_xor(lacc[tr], 16);
        lacc[tr] += __shfl_xor(lacc[tr], 32);
        float linv = 1.0f / lacc[tr];
        if (lane < 16) lin[(size_t)bh * T_DIM + tbase + tr * 16 + m] = linv;
#pragma unroll
        for (int r = 0; r < 4; ++r) {
            float lr = __shfl(linv, g * 4 + r);   // l for t-row g*4+r
            int t = tbase + tr * 16 + g * 4 + r;
#pragma unroll
            for (int dd = 0; dd < 4; ++dd)
                Xb[((size_t)t * B_DIM + b) * E_DIM + h * 64 + dd * 16 + m] =
                    f2bf(O[tr][dd][r] * lr);
        }
    }
}

// ---------------------------------------------------------------------------
// K2: attn_avg -> out1 (B,T,S) fp32.
// s-tile 64 -> grid (b, t128, s64) = 1024 blocks (4 blocks/CU), LDS 18 KB,
// per-h Q-frag + lin loads software-pipelined one head ahead.
// exp arg needs no fma (scale folded into qb).
// ---------------------------------------------------------------------------
__global__ __launch_bounds__(256, 4) void attn_avg(
    const u16* __restrict__ qb, const u16* __restrict__ ks,
    const float* __restrict__ lin, float* __restrict__ out1) {
    __shared__ u16 Kl[2][64 * PITCH];   // 18 KB
    int bx = blockIdx.x;
    int b = bx >> 9;
    int tt = (bx >> 5) & 15;
    int st = bx & 31;
    int tid = threadIdx.x;
    int w = tid >> 6;
    int tbase = tt * 128 + w * 32;
    int sbase = st * 64;
    int lane = tid & 63, m = lane & 15, g = lane >> 4;

    // staging: thread -> (row 0..63, 16-elem quarter), 32 B/thread
    int srow = tid >> 2;
    int sqtr = (tid & 3) * 16;

    uint4 kr0, kr1;
    auto load_stage = [&](int h) {
        const uint4* kp = reinterpret_cast<const uint4*>(
            ks + ((size_t)(b * 16 + h) * S_DIM + sbase + srow) * 64 + sqtr);
        kr0 = kp[0]; kr1 = kp[1];
    };
    auto write_stage = [&](int buf) {
        uint4* kd = reinterpret_cast<uint4*>(&Kl[buf][srow * PITCH + sqtr]);
        kd[0] = kr0; kd[1] = kr1;
    };

    v8s aqc00, aqc01, aqc10, aqc11, aqn00, aqn01, aqn10, aqn11;
    float livc[2][4], livn[2][4];
    auto load_q = [&](int h, v8s& a00, v8s& a01, v8s& a10, v8s& a11, float (&liv)[2][4]) {
        int bh = b * 16 + h;
        const u16* qrow = qb + ((size_t)bh * T_DIM + tbase + m) * 64 + g * 8;
        a00 = ld8(qrow);        a01 = ld8(qrow + 32);
        a10 = ld8(qrow + 1024); a11 = ld8(qrow + 1024 + 32);
#pragma unroll
        for (int tr = 0; tr < 2; ++tr)
#pragma unroll
            for (int r = 0; r < 4; ++r)
                liv[tr][r] = lin[(size_t)bh * T_DIM + tbase + tr * 16 + g * 4 + r] * (1.0f / 16.0f);
    };

    v4f AVG[2][4];
#pragma unroll
    for (int tr = 0; tr < 2; ++tr)
#pragma unroll
        for (int ss = 0; ss < 4; ++ss) AVG[tr][ss] = (v4f){0.f, 0.f, 0.f, 0.f};

    load_stage(0);
    write_stage(0);
    load_stage(1);
    load_q(0, aqc00, aqc01, aqc10, aqc11, livc);
    __syncthreads();

    for (int h = 0; h < H_DIM; ++h) {
        int buf = h & 1;
        // prefetch next head's Q-frags + lin (latency hidden under compute)
        if (h + 1 < H_DIM) load_q(h + 1, aqn00, aqn01, aqn10, aqn11, livn);

        const u16* Kb = Kl[buf];
#pragma unroll
        for (int ss = 0; ss < 4; ++ss) {
            v8s kf0 = ld8(&Kb[(ss * 16 + m) * PITCH + g * 8]);
            v8s kf1 = ld8(&Kb[(ss * 16 + m) * PITCH + 32 + g * 8]);
            {
                v4f z = {0.f, 0.f, 0.f, 0.f};
                z = mfma16(aqc00, kf0, z);
                z = mfma16(aqc01, kf1, z);
#pragma unroll
                for (int r = 0; r < 4; ++r)
                    AVG[0][ss][r] += EXP2(z[r]) * livc[0][r];
            }
            {
                v4f z = {0.f, 0.f, 0.f, 0.f};
                z = mfma16(aqc10, kf0, z);
                z = mfma16(aqc11, kf1, z);
#pragma unroll
                for (int r = 0; r < 4; ++r)
                    AVG[1][ss][r] += EXP2(z[r]) * livc[1][r];
            }
        }
        if (h + 1 < H_DIM) {
            write_stage(buf ^ 1);
            if (h + 2 < H_DIM) load_stage(h + 2);
        }
        __syncthreads();
        // rotate prefetched regs into current
        aqc00 = aqn00; aqc01 = aqn01; aqc10 = aqn10; aqc11 = aqn11;
#pragma unroll
        for (int tr = 0; tr < 2; ++tr)
#pragma unroll
            for (int r = 0; r < 4; ++r) livc[tr][r] = livn[tr][r];
    }
#pragma unroll
    for (int tr = 0; tr < 2; ++tr)
#pragma unroll
        for (int ss = 0; ss < 4; ++ss)
#pragma unroll
            for (int r = 0; r < 4; ++r) {
                int t = tbase + tr * 16 + g * 4 + r;
                out1[((size_t)b * T_DIM + t) * S_DIM + sbase + ss * 16 + m] = AVG[tr][ss][r];
            }
}

// ---------------------------------------------------------------------------
// K3: out0 = Xb @ Wb^T + bias + query, fp32 out. grid 64 x 8 = 512 blocks.
// LDS-staged double-buffered GEMM (register-relay). Tile 64x128, BK=64.
// ---------------------------------------------------------------------------
__global__ __launch_bounds__(256) void linear_mfma(
    const u16* __restrict__ Xb, const u16* __restrict__ Wb,
    const float* __restrict__ bias, const float* __restrict__ query,
    float* __restrict__ out0) {
    __shared__ u16 Al[2][64 * PITCH];    // 18 KB
    __shared__ u16 Wl[2][128 * PITCH];   // 36 KB
    int bx = blockIdx.x;
    int it = bx >> 3, jt = bx & 7;
    int tid = threadIdx.x;
    int w = tid >> 6;
    int lane = tid & 63;
    int m = lane & 15, g = lane >> 4;

    // staging maps (register relay)
    int arow = tid >> 2, aq4 = (tid & 3) * 16;   // A: 64 rows x 32 B per thread
    int wrow = tid >> 1, wh2 = (tid & 1) * 32;   // W: 128 rows x 64 B per thread

    uint4 ar0, ar1, wr0, wr1, wr2, wr3;
    auto load_stage = [&](int k0) {
        const uint4* ap = reinterpret_cast<const uint4*>(
            Xb + (size_t)(it * 64 + arow) * E_DIM + k0 + aq4);
        ar0 = ap[0]; ar1 = ap[1];
        const uint4* wp = reinterpret_cast<const uint4*>(
            Wb + (size_t)(jt * 128 + wrow) * E_DIM + k0 + wh2);
        wr0 = wp[0]; wr1 = wp[1]; wr2 = wp[2]; wr3 = wp[3];
    };
    auto write_stage = [&](int buf) {
        uint4* ad = reinterpret_cast<uint4*>(&Al[buf][arow * PITCH + aq4]);
        ad[0] = ar0; ad[1] = ar1;
        uint4* wd = reinterpret_cast<uint4*>(&Wl[buf][wrow * PITCH + wh2]);
        wd[0] = wr0; wd[1] = wr1; wd[2] = wr2; wd[3] = wr3;
    };

    v4f acc[4][2];
#pragma unroll
    for (int tr = 0; tr < 4; ++tr)
#pragma unroll
        for (int nn = 0; nn < 2; ++nn) acc[tr][nn] = (v4f){0.f, 0.f, 0.f, 0.f};

    load_stage(0);
    write_stage(0);
    load_stage(64);
    __syncthreads();

    for (int itk = 0; itk < 16; ++itk) {
        int buf = itk & 1;
        const u16* Ab = Al[buf];
        const u16* Ws = Wl[buf];
        v8s af[4][2], wf[2][2];
#pragma unroll
        for (int tr = 0; tr < 4; ++tr) {
            af[tr][0] = ld8(&Ab[(tr * 16 + m) * PITCH + g * 8]);
            af[tr][1] = ld8(&Ab[(tr * 16 + m) * PITCH + 32 + g * 8]);
        }
#pragma unroll
        for (int nn = 0; nn < 2; ++nn) {
            wf[nn][0] = ld8(&Ws[((w * 2 + nn) * 16 + m) * PITCH + g * 8]);
            wf[nn][1] = ld8(&Ws[((w * 2 + nn) * 16 + m) * PITCH + 32 + g * 8]);
        }
#pragma unroll
        for (int tr = 0; tr < 4; ++tr)
#pragma unroll
            for (int nn = 0; nn < 2; ++nn) {
                acc[tr][nn] = mfma16(af[tr][0], wf[nn][0], acc[tr][nn]);
                acc[tr][nn] = mfma16(af[tr][1], wf[nn][1], acc[tr][nn]);
            }
        // relay: stage next tile, prefetch tile after
        if (itk + 1 < 16) {
            write_stage(buf ^ 1);
            if (itk + 2 < 16) load_stage((itk + 2) * 64);
        }
        __syncthreads();
    }

    // epilogue: bias + residual(query) + fp32 store
#pragma unroll
    for (int tr = 0; tr < 4; ++tr)
#pragma unroll
        for (int nn = 0; nn < 2; ++nn) {
            int col = jt * 128 + (w * 2 + nn) * 16 + m;
            float bv = bias[col];
#pragma unroll
            for (int r = 0; r < 4; ++r) {
                int row = it * 64 + tr * 16 + g * 4 + r;
                out0[(size_t)row * E_DIM + col] =
                    acc[tr][nn][r] + bv + query[(size_t)row * E_DIM + col];
            }
        }
}

// ---------------------------------------------------------------------------
extern "C" void kernel_launch(void* const* d_in, const int* in_sizes, int n_in,
                              void* d_out, int out_size, void* d_ws, size_t ws_size,
                              hipStream_t stream) {
    const float* query = (const float*)d_in[0];
    const float* key   = (const float*)d_in[1];
    const float* value = (const float*)d_in[2];
    const float* qpos  = (const float*)d_in[3];
    const float* kpos  = (const float*)d_in[4];
    const float* W     = (const float*)d_in[5];
    const float* bias  = (const float*)d_in[6];

    char* ws = (char*)d_ws;
    u16*   qb  = (u16*)(ws);                              //  8 MB
    u16*   ks  = (u16*)(ws + (size_t)( 8u << 20));        //  8 MB
    u16*   vt  = (u16*)(ws + (size_t)(16u << 20));        //  8 MB
    u16*   Wb  = (u16*)(ws + (size_t)(24u << 20));        //  2 MB
    float* lin = (float*)(ws + (size_t)(26u << 20));      // 256 KB
    u16*   Xb  = (u16*)(ws + (size_t)(27u << 20));        //  8 MB (35 MB total)

    float* out0 = (float*)d_out;
    float* out1 = out0 + (size_t)T_DIM * B_DIM * E_DIM;

    prep_qk<<<(B_DIM * H_DIM * T_DIM * D_DIM) / 256, 256, 0, stream>>>(query, qpos, key, kpos, W, qb, ks, Wb);
    prep_vt<<<B_DIM * H_DIM * (S_DIM / 64), 256, 0, stream>>>(value, vt);
    attn_pv<<<B_DIM * H_DIM * (T_DIM / 128), 256, 0, stream>>>(qb, ks, vt, lin, Xb);
    attn_avg<<<B_DIM * (T_DIM / 128) * (S_DIM / 64), 256, 0, stream>>>(qb, ks, lin, out1);
    linear_mfma<<<(T_DIM * B_DIM / 64) * (E_DIM / 128), 256, 0, stream>>>(Xb, Wb, bias, query, out0);
}

// Round 14
// 254.481 us; speedup vs baseline: 1.0784x; 1.0111x over previous
//
#include <hip/hip_runtime.h>
#include <hip/hip_bf16.h>

#define T_DIM 2048
#define S_DIM 2048
#define B_DIM 2
#define E_DIM 1024
#define H_DIM 16
#define D_DIM 64
// softmax scale 0.125 and the 1/ln2 of exp are folded into qb at prep time:
// qb = bf16((q+qpos) * 0.125*log2(e)); then P = exp2(qb.k) exactly (no shift:
// shift cancels in P/l and e*lin; |z|<~43 so exp2(z), l stay in fp32 range).
#define EXP2S 0.18033688f
#define EXP2(x) __builtin_amdgcn_exp2f(x)

typedef unsigned short u16;
typedef unsigned int u32;
typedef float v4f __attribute__((ext_vector_type(4)));
typedef short v8s __attribute__((ext_vector_type(8)));
typedef short v4s __attribute__((ext_vector_type(4)));

__device__ __forceinline__ u16 f2bf(float f) {   // RNE
    union { float f; u32 u; } x; x.f = f;
    return (u16)((x.u + 0x7fffu + ((x.u >> 16) & 1u)) >> 16);
}
__device__ __forceinline__ u32 pkrn(float lo, float hi) {  // packed bf16 pair
    union { __hip_bfloat162 h; u32 u; } c;
    c.h = __float22bfloat162_rn(make_float2(lo, hi));
    return c.u;
}
__device__ __forceinline__ v4f mfma16(v8s a, v8s b, v4f c) {
    return __builtin_amdgcn_mfma_f32_16x16x32_bf16(a, b, c, 0, 0, 0);
}
__device__ __forceinline__ v4f mfma16x16(v4s a, v4s b, v4f c) {
    return __builtin_amdgcn_mfma_f32_16x16x16bf16_1k(a, b, c, 0, 0, 0);
}
__device__ __forceinline__ v8s ld8(const u16* p) {
    return *reinterpret_cast<const v8s*>(p);
}

// ---------------------------------------------------------------------------
// K0a: qb = bf16((q+qpos)*EXP2S); ks = bf16(k+kpos); Wb = bf16(W) (fused).
// ---------------------------------------------------------------------------
__global__ __launch_bounds__(256) void prep_qk(
    const float* __restrict__ q, const float* __restrict__ qp,
    const float* __restrict__ k, const float* __restrict__ kp,
    const float* __restrict__ W,
    u16* __restrict__ qb, u16* __restrict__ ks, u16* __restrict__ Wb) {
    int o = blockIdx.x * 256 + threadIdx.x;          // (b,h,t,d)
    int d = o & 63, t = (o >> 6) & 2047, h = (o >> 17) & 15, b = o >> 21;
    int src = ((t * B_DIM + b) << 10) + (h << 6) + d; // (t,b,e)
    qb[o] = f2bf((q[src] + qp[src]) * EXP2S);
    ks[o] = f2bf(k[src] + kp[src]);
    if (o < E_DIM * E_DIM) Wb[o] = f2bf(W[o]);       // fused prep_w
}

// K0c: vt[b][h][d][s] = bf16(V[s][b][h*64+d])  — tiled transpose
__global__ __launch_bounds__(256) void prep_vt(const float* __restrict__ V, u16* __restrict__ vt) {
    __shared__ float tile[64 * 65];
    int bx = blockIdx.x;                 // (bh, s-tile): 32 bh * 32 stiles
    int bh = bx >> 5;
    int s0 = (bx & 31) * 64;
    int b = bh >> 4, h = bh & 15;
    int tid = threadIdx.x;
    int quarter = tid >> 6, c = tid & 63;
    int boff = b * E_DIM + h * 64;
#pragma unroll
    for (int p = 0; p < 16; ++p) {
        int r = quarter * 16 + p;
        tile[r * 65 + c] = V[(size_t)(s0 + r) * (B_DIM * E_DIM) + boff + c];
    }
    __syncthreads();
#pragma unroll
    for (int p = 0; p < 16; ++p) {
        int d = quarter * 16 + p;
        vt[(size_t)bh * (D_DIM * S_DIM) + (size_t)d * S_DIM + s0 + c] = f2bf(tile[c * 65 + d]);
    }
}

// ---------------------------------------------------------------------------
// K1: attention output + row sums. grid (bh, t-tile128) = 512 blocks, 256 thr.
// Swapped QK^T -> P in registers (16x16x16 A-frag layout); PV reg-direct.
// v6: l-accumulation moved from VALU to the MFMA pipe via a constant
// all-ones B-fragment: O_l = mfma(pa, ONES, O_l) gives P row-sums in the
// SAME lane/reg layout as O -> epilogue needs no shfl at all.
// K/V s-tile 64 in LDS, double-buffered via register relay. No setprio.
// ---------------------------------------------------------------------------
#define PITCH 72   // 64 elems + 8 pad (144 B rows)
__global__ __launch_bounds__(256) void attn_pv(
    const u16* __restrict__ qb, const u16* __restrict__ ks, const u16* __restrict__ vt,
    float* __restrict__ lin, u16* __restrict__ Xb) {
    __shared__ u16 Kl[2][64 * PITCH];   // 18 KB
    __shared__ u16 Vl[2][64 * PITCH];   // 18 KB

    int bx = blockIdx.x;
    int bh = bx >> 4;
    int b = bh >> 4, h = bh & 15;
    int tid = threadIdx.x;
    int w = tid >> 6;
    int tbase = (bx & 15) * 128 + w * 32;
    int lane = tid & 63;
    int m = lane & 15, g = lane >> 4;

    // staging: thread -> (row 0..63, 16-elem quarter)
    int srow = tid >> 2;
    int sqtr = (tid & 3) * 16;

    uint4 kr0, kr1, vr0, vr1;
    auto load_stage = [&](int s0) {
        const uint4* kp = reinterpret_cast<const uint4*>(
            ks + ((size_t)bh * S_DIM + s0 + srow) * 64 + sqtr);
        kr0 = kp[0]; kr1 = kp[1];
        const uint4* vp = reinterpret_cast<const uint4*>(
            vt + (size_t)bh * (D_DIM * S_DIM) + (size_t)srow * S_DIM + s0 + sqtr);
        vr0 = vp[0]; vr1 = vp[1];
    };
    auto write_stage = [&](int buf) {
        uint4* kd = reinterpret_cast<uint4*>(&Kl[buf][srow * PITCH + sqtr]);
        kd[0] = kr0; kd[1] = kr1;
        uint4* vd = reinterpret_cast<uint4*>(&Vl[buf][srow * PITCH + sqtr]);
        vd[0] = vr0; vd[1] = vr1;
    };

    // Q-frags (B-operand of swapped QK): 2 groups of 16 t-rows
    const u16* qrow = qb + ((size_t)bh * T_DIM + tbase + m) * 64 + g * 8;
    v8s aq[2][2];
    aq[0][0] = ld8(qrow);        aq[0][1] = ld8(qrow + 32);
    aq[1][0] = ld8(qrow + 1024); aq[1][1] = ld8(qrow + 1024 + 32);

    // constant all-ones B-frag (bf16 1.0 = 0x3F80)
    const v4s ONES = {(short)0x3F80, (short)0x3F80, (short)0x3F80, (short)0x3F80};

    v4f O[2][4];
    v4f Ol[2];   // P row-sums (l), same layout as O
#pragma unroll
    for (int tr = 0; tr < 2; ++tr) {
        Ol[tr] = (v4f){0.f, 0.f, 0.f, 0.f};
#pragma unroll
        for (int dd = 0; dd < 4; ++dd) O[tr][dd] = (v4f){0.f, 0.f, 0.f, 0.f};
    }

    load_stage(0);
    write_stage(0);
    load_stage(64);
    __syncthreads();

    for (int it = 0; it < 32; ++it) {
        int buf = it & 1;
        const u16* Kb = Kl[buf];
        const u16* Vb = Vl[buf];
#pragma unroll
        for (int ss = 0; ss < 4; ++ss) {
            v8s kf0 = ld8(&Kb[(ss * 16 + m) * PITCH + g * 8]);
            v8s kf1 = ld8(&Kb[(ss * 16 + m) * PITCH + 32 + g * 8]);
            v4s pa0, pa1;
            {   // tr = 0: z rows = s (16ss+4g+r), cols = t (tbase+m)
                v4f z = {0.f, 0.f, 0.f, 0.f};
                z = mfma16(kf0, aq[0][0], z);
                z = mfma16(kf1, aq[0][1], z);
                float e0 = EXP2(z[0]);
                float e1 = EXP2(z[1]);
                float e2 = EXP2(z[2]);
                float e3 = EXP2(z[3]);
                union { u32 u[2]; v4s s; } pk_;
                pk_.u[0] = pkrn(e0, e1);
                pk_.u[1] = pkrn(e2, e3);
                pa0 = pk_.s;
            }
            {   // tr = 1
                v4f z = {0.f, 0.f, 0.f, 0.f};
                z = mfma16(kf0, aq[1][0], z);
                z = mfma16(kf1, aq[1][1], z);
                float e0 = EXP2(z[0]);
                float e1 = EXP2(z[1]);
                float e2 = EXP2(z[2]);
                float e3 = EXP2(z[3]);
                union { u32 u[2]; v4s s; } pk_;
                pk_.u[0] = pkrn(e0, e1);
                pk_.u[1] = pkrn(e2, e3);
                pa1 = pk_.s;
            }
            // l row-sums on the MFMA pipe (B = ones)
            Ol[0] = mfma16x16(pa0, ONES, Ol[0]);
            Ol[1] = mfma16x16(pa1, ONES, Ol[1]);
            // PV for this ss-block: B-frag = V[s=16ss+4g+j][d=dd*16+m] (8B read)
#pragma unroll
            for (int dd = 0; dd < 4; ++dd) {
                v4s bv = *reinterpret_cast<const v4s*>(
                    &Vb[(dd * 16 + m) * PITCH + ss * 16 + g * 4]);
                O[0][dd] = mfma16x16(pa0, bv, O[0][dd]);
                O[1][dd] = mfma16x16(pa1, bv, O[1][dd]);
            }
        }
        // ---- relay: stage next tile, prefetch tile after ----
        if (it + 1 < 32) {
            write_stage(buf ^ 1);
            if (it + 2 < 32) load_stage((it + 2) * 64);
        }
        __syncthreads();
    }

    // Ol[tr][r] = l for t = tbase + tr*16 + g*4 + r (same layout as O) —
    // no cross-lane reduce needed.
#pragma unroll
    for (int tr = 0; tr < 2; ++tr) {
#pragma unroll
        for (int r = 0; r < 4; ++r) {
            float linv = 1.0f / Ol[tr][r];
            int t = tbase + tr * 16 + g * 4 + r;
            if (m == 0) lin[(size_t)bh * T_DIM + t] = linv;
#pragma unroll
            for (int dd = 0; dd < 4; ++dd)
                Xb[((size_t)t * B_DIM + b) * E_DIM + h * 64 + dd * 16 + m] =
                    f2bf(O[tr][dd][r] * linv);
        }
    }
}

// ---------------------------------------------------------------------------
// K2: attn_avg -> out1 (B,T,S) fp32.
// s-tile 64 -> grid (b, t128, s64) = 1024 blocks (4 blocks/CU), LDS 18 KB,
// per-h Q-frag + lin loads software-pipelined one head ahead.
// exp arg needs no fma (scale folded into qb).
// ---------------------------------------------------------------------------
__global__ __launch_bounds__(256, 4) void attn_avg(
    const u16* __restrict__ qb, const u16* __restrict__ ks,
    const float* __restrict__ lin, float* __restrict__ out1) {
    __shared__ u16 Kl[2][64 * PITCH];   // 18 KB
    int bx = blockIdx.x;
    int b = bx >> 9;
    int tt = (bx >> 5) & 15;
    int st = bx & 31;
    int tid = threadIdx.x;
    int w = tid >> 6;
    int tbase = tt * 128 + w * 32;
    int sbase = st * 64;
    int lane = tid & 63, m = lane & 15, g = lane >> 4;

    // staging: thread -> (row 0..63, 16-elem quarter), 32 B/thread
    int srow = tid >> 2;
    int sqtr = (tid & 3) * 16;

    uint4 kr0, kr1;
    auto load_stage = [&](int h) {
        const uint4* kp = reinterpret_cast<const uint4*>(
            ks + ((size_t)(b * 16 + h) * S_DIM + sbase + srow) * 64 + sqtr);
        kr0 = kp[0]; kr1 = kp[1];
    };
    auto write_stage = [&](int buf) {
        uint4* kd = reinterpret_cast<uint4*>(&Kl[buf][srow * PITCH + sqtr]);
        kd[0] = kr0; kd[1] = kr1;
    };

    v8s aqc00, aqc01, aqc10, aqc11, aqn00, aqn01, aqn10, aqn11;
    float livc[2][4], livn[2][4];
    auto load_q = [&](int h, v8s& a00, v8s& a01, v8s& a10, v8s& a11, float (&liv)[2][4]) {
        int bh = b * 16 + h;
        const u16* qrow = qb + ((size_t)bh * T_DIM + tbase + m) * 64 + g * 8;
        a00 = ld8(qrow);        a01 = ld8(qrow + 32);
        a10 = ld8(qrow + 1024); a11 = ld8(qrow + 1024 + 32);
#pragma unroll
        for (int tr = 0; tr < 2; ++tr)
#pragma unroll
            for (int r = 0; r < 4; ++r)
                liv[tr][r] = lin[(size_t)bh * T_DIM + tbase + tr * 16 + g * 4 + r] * (1.0f / 16.0f);
    };

    v4f AVG[2][4];
#pragma unroll
    for (int tr = 0; tr < 2; ++tr)
#pragma unroll
        for (int ss = 0; ss < 4; ++ss) AVG[tr][ss] = (v4f){0.f, 0.f, 0.f, 0.f};

    load_stage(0);
    write_stage(0);
    load_stage(1);
    load_q(0, aqc00, aqc01, aqc10, aqc11, livc);
    __syncthreads();

    for (int h = 0; h < H_DIM; ++h) {
        int buf = h & 1;
        // prefetch next head's Q-frags + lin (latency hidden under compute)
        if (h + 1 < H_DIM) load_q(h + 1, aqn00, aqn01, aqn10, aqn11, livn);

        const u16* Kb = Kl[buf];
#pragma unroll
        for (int ss = 0; ss < 4; ++ss) {
            v8s kf0 = ld8(&Kb[(ss * 16 + m) * PITCH + g * 8]);
            v8s kf1 = ld8(&Kb[(ss * 16 + m) * PITCH + 32 + g * 8]);
            {
                v4f z = {0.f, 0.f, 0.f, 0.f};
                z = mfma16(aqc00, kf0, z);
                z = mfma16(aqc01, kf1, z);
#pragma unroll
                for (int r = 0; r < 4; ++r)
                    AVG[0][ss][r] += EXP2(z[r]) * livc[0][r];
            }
            {
                v4f z = {0.f, 0.f, 0.f, 0.f};
                z = mfma16(aqc10, kf0, z);
                z = mfma16(aqc11, kf1, z);
#pragma unroll
                for (int r = 0; r < 4; ++r)
                    AVG[1][ss][r] += EXP2(z[r]) * livc[1][r];
            }
        }
        if (h + 1 < H_DIM) {
            write_stage(buf ^ 1);
            if (h + 2 < H_DIM) load_stage(h + 2);
        }
        __syncthreads();
        // rotate prefetched regs into current
        aqc00 = aqn00; aqc01 = aqn01; aqc10 = aqn10; aqc11 = aqn11;
#pragma unroll
        for (int tr = 0; tr < 2; ++tr)
#pragma unroll
            for (int r = 0; r < 4; ++r) livc[tr][r] = livn[tr][r];
    }
#pragma unroll
    for (int tr = 0; tr < 2; ++tr)
#pragma unroll
        for (int ss = 0; ss < 4; ++ss)
#pragma unroll
            for (int r = 0; r < 4; ++r) {
                int t = tbase + tr * 16 + g * 4 + r;
                out1[((size_t)b * T_DIM + t) * S_DIM + sbase + ss * 16 + m] = AVG[tr][ss][r];
            }
}

// ---------------------------------------------------------------------------
// K3: out0 = Xb @ Wb^T + bias + query, fp32 out. grid 64 x 8 = 512 blocks.
// LDS-staged double-buffered GEMM (register-relay). Tile 64x128, BK=64.
// ---------------------------------------------------------------------------
__global__ __launch_bounds__(256) void linear_mfma(
    const u16* __restrict__ Xb, const u16* __restrict__ Wb,
    const float* __restrict__ bias, const float* __restrict__ query,
    float* __restrict__ out0) {
    __shared__ u16 Al[2][64 * PITCH];    // 18 KB
    __shared__ u16 Wl[2][128 * PITCH];   // 36 KB
    int bx = blockIdx.x;
    int it = bx >> 3, jt = bx & 7;
    int tid = threadIdx.x;
    int w = tid >> 6;
    int lane = tid & 63;
    int m = lane & 15, g = lane >> 4;

    // staging maps (register relay)
    int arow = tid >> 2, aq4 = (tid & 3) * 16;   // A: 64 rows x 32 B per thread
    int wrow = tid >> 1, wh2 = (tid & 1) * 32;   // W: 128 rows x 64 B per thread

    uint4 ar0, ar1, wr0, wr1, wr2, wr3;
    auto load_stage = [&](int k0) {
        const uint4* ap = reinterpret_cast<const uint4*>(
            Xb + (size_t)(it * 64 + arow) * E_DIM + k0 + aq4);
        ar0 = ap[0]; ar1 = ap[1];
        const uint4* wp = reinterpret_cast<const uint4*>(
            Wb + (size_t)(jt * 128 + wrow) * E_DIM + k0 + wh2);
        wr0 = wp[0]; wr1 = wp[1]; wr2 = wp[2]; wr3 = wp[3];
    };
    auto write_stage = [&](int buf) {
        uint4* ad = reinterpret_cast<uint4*>(&Al[buf][arow * PITCH + aq4]);
        ad[0] = ar0; ad[1] = ar1;
        uint4* wd = reinterpret_cast<uint4*>(&Wl[buf][wrow * PITCH + wh2]);
        wd[0] = wr0; wd[1] = wr1; wd[2] = wr2; wd[3] = wr3;
    };

    v4f acc[4][2];
#pragma unroll
    for (int tr = 0; tr < 4; ++tr)
#pragma unroll
        for (int nn = 0; nn < 2; ++nn) acc[tr][nn] = (v4f){0.f, 0.f, 0.f, 0.f};

    load_stage(0);
    write_stage(0);
    load_stage(64);
    __syncthreads();

    for (int itk = 0; itk < 16; ++itk) {
        int buf = itk & 1;
        const u16* Ab = Al[buf];
        const u16* Ws = Wl[buf];
        v8s af[4][2], wf[2][2];
#pragma unroll
        for (int tr = 0; tr < 4; ++tr) {
            af[tr][0] = ld8(&Ab[(tr * 16 + m) * PITCH + g * 8]);
            af[tr][1] = ld8(&Ab[(tr * 16 + m) * PITCH + 32 + g * 8]);
        }
#pragma unroll
        for (int nn = 0; nn < 2; ++nn) {
            wf[nn][0] = ld8(&Ws[((w * 2 + nn) * 16 + m) * PITCH + g * 8]);
            wf[nn][1] = ld8(&Ws[((w * 2 + nn) * 16 + m) * PITCH + 32 + g * 8]);
        }
#pragma unroll
        for (int tr = 0; tr < 4; ++tr)
#pragma unroll
            for (int nn = 0; nn < 2; ++nn) {
                acc[tr][nn] = mfma16(af[tr][0], wf[nn][0], acc[tr][nn]);
                acc[tr][nn] = mfma16(af[tr][1], wf[nn][1], acc[tr][nn]);
            }
        // relay: stage next tile, prefetch tile after
        if (itk + 1 < 16) {
            write_stage(buf ^ 1);
            if (itk + 2 < 16) load_stage((itk + 2) * 64);
        }
        __syncthreads();
    }

    // epilogue: bias + residual(query) + fp32 store
#pragma unroll
    for (int tr = 0; tr < 4; ++tr)
#pragma unroll
        for (int nn = 0; nn < 2; ++nn) {
            int col = jt * 128 + (w * 2 + nn) * 16 + m;
            float bv = bias[col];
#pragma unroll
            for (int r = 0; r < 4; ++r) {
                int row = it * 64 + tr * 16 + g * 4 + r;
                out0[(size_t)row * E_DIM + col] =
                    acc[tr][nn][r] + bv + query[(size_t)row * E_DIM + col];
            }
        }
}

// ---------------------------------------------------------------------------
extern "C" void kernel_launch(void* const* d_in, const int* in_sizes, int n_in,
                              void* d_out, int out_size, void* d_ws, size_t ws_size,
                              hipStream_t stream) {
    const float* query = (const float*)d_in[0];
    const float* key   = (const float*)d_in[1];
    const float* value = (const float*)d_in[2];
    const float* qpos  = (const float*)d_in[3];
    const float* kpos  = (const float*)d_in[4];
    const float* W     = (const float*)d_in[5];
    const float* bias  = (const float*)d_in[6];

    char* ws = (char*)d_ws;
    u16*   qb  = (u16*)(ws);                              //  8 MB
    u16*   ks  = (u16*)(ws + (size_t)( 8u << 20));        //  8 MB
    u16*   vt  = (u16*)(ws + (size_t)(16u << 20));        //  8 MB
    u16*   Wb  = (u16*)(ws + (size_t)(24u << 20));        //  2 MB
    float* lin = (float*)(ws + (size_t)(26u << 20));      // 256 KB
    u16*   Xb  = (u16*)(ws + (size_t)(27u << 20));        //  8 MB (35 MB total)

    float* out0 = (float*)d_out;
    float* out1 = out0 + (size_t)T_DIM * B_DIM * E_DIM;

    prep_qk<<<(B_DIM * H_DIM * T_DIM * D_DIM) / 256, 256, 0, stream>>>(query, qpos, key, kpos, W, qb, ks, Wb);
    prep_vt<<<B_DIM * H_DIM * (S_DIM / 64), 256, 0, stream>>>(value, vt);
    attn_pv<<<B_DIM * H_DIM * (T_DIM / 128), 256, 0, stream>>>(qb, ks, vt, lin, Xb);
    attn_avg<<<B_DIM * (T_DIM / 128) * (S_DIM / 64), 256, 0, stream>>>(qb, ks, lin, out1);
    linear_mfma<<<(T_DIM * B_DIM / 64) * (E_DIM / 128), 256, 0, stream>>>(Xb, Wb, bias, query, out0);
}